// Round 2
// baseline (740.691 us; speedup 1.0000x reference)
//
#include <hip/hip_runtime.h>

// ROI head: pool -> x@W1 relu -> @W2 relu -> @[W_loc|W_score]
// HBM-bound on fp32 weight streaming (~480MB). Big GEMMs: LDS-staged via
// global_load_lds dwordx4, 3-buffer ring with stage-distance 2 and COUNTED
// s_waitcnt vmcnt(3) + raw s_barrier (never drain prefetch in main loop).
// Pool: fully-unrolled 7x7 bins x predicated 4x4 windows (ROI<=256px =>
// window<=4), no runtime-indexed per-thread arrays (scratch-free).

typedef short short8 __attribute__((ext_vector_type(8)));
typedef float f32x4 __attribute__((ext_vector_type(4)));

__device__ __forceinline__ unsigned short bf16_rne(float f) {
    unsigned int u = __builtin_bit_cast(unsigned int, f);
    unsigned int r = (u + 0x7FFFu + ((u >> 16) & 1u)) >> 16;
    return (unsigned short)r;
}

// async global->LDS, 16B per lane; lptr must be wave-uniform (HW scatters
// lane i to lptr + 16*i). gptr is per-lane.
__device__ __forceinline__ void gl16(const void* g, void* l) {
    __builtin_amdgcn_global_load_lds(
        (const __attribute__((address_space(1))) unsigned int*)g,
        (__attribute__((address_space(3))) unsigned int*)l, 16, 0, 0);
}

// ---------------- transpose F[512][1900] -> FT[1900][512] -------------------
__global__ void transpose_kernel(const float* __restrict__ F,
                                 float* __restrict__ FT)
{
    __shared__ float t[32][33];
    const int xs = blockIdx.x * 32;   // spatial 0..1899
    const int cs = blockIdx.y * 32;   // channel 0..511
    const int tx = threadIdx.x, ty = threadIdx.y;  // 32 x 8
#pragma unroll
    for (int k = 0; k < 4; ++k) {
        int cc = cs + ty + k * 8;
        int xx = xs + tx;
        if (xx < 1900) t[ty + k * 8][tx] = F[cc * 1900 + xx];
    }
    __syncthreads();
#pragma unroll
    for (int k = 0; k < 4; ++k) {
        int xx = xs + ty + k * 8;
        int cc = cs + tx;
        if (xx < 1900) FT[xx * 512 + cc] = t[tx][ty + k * 8];
    }
}

// ---------------- pooling: FT[1900][512] -> X bf16 [128][25088] -------------
// ROI sides <= 256px/16 + 1 = 17 feature px => each adaptive bin window is
// <= ceil(17/7)+1 = 4 wide per axis. Fully unrolled, predicated 4x4 windows:
// all indices compile-time => bin bounds stay in registers, loads independent.
__global__ void pool_kernel(const float* __restrict__ FT,
                            const float* __restrict__ rois,
                            unsigned short* __restrict__ X)
{
    __shared__ unsigned short tile[256 * 49];
    const int r = blockIdx.x;
    const int c = blockIdx.y * 256 + threadIdx.x;   // channel
    const float4 rv = ((const float4*)rois)[r];
    const int y0 = (int)truncf(rv.x * 0.0625f);
    const int x0 = (int)truncf(rv.y * 0.0625f);
    const int y2 = (int)ceilf (rv.z * 0.0625f);
    const int x3 = (int)ceilf (rv.w * 0.0625f);
    const int Ly = y2 - y0, Lx = x3 - x0;

    int rb[7], re[7], cb[7], ce[7];
#pragma unroll
    for (int i = 0; i < 7; ++i) {
        rb[i] = y0 + (i * Ly) / 7;
        re[i] = min(min(y0 + ((i + 1) * Ly + 6) / 7, rb[i] + 4), 38);
        cb[i] = x0 + (i * Lx) / 7;
        ce[i] = min(min(x0 + ((i + 1) * Lx + 6) / 7, cb[i] + 4), 50);
    }

    const float* base = FT + (size_t)c;
#pragma unroll
    for (int i = 0; i < 7; ++i) {
#pragma unroll
        for (int j = 0; j < 7; ++j) {
            const int r0 = rb[i], r1 = re[i];
            const int c0 = cb[j], c1 = ce[j];
            float m = -3.4e38f;
#pragma unroll
            for (int dr = 0; dr < 4; ++dr) {
#pragma unroll
                for (int dc = 0; dc < 4; ++dc) {
                    const int rr = r0 + dr, cc = c0 + dc;
                    const bool ok = (rr < r1) && (cc < c1);
                    const int rrc = ok ? rr : r0;     // clamped in-bounds addr
                    const int ccc = ok ? cc : c0;
                    float v = base[(size_t)(rrc * 50 + ccc) * 512];
                    m = fmaxf(m, ok ? v : -3.4e38f);
                }
            }
            tile[threadIdx.x * 49 + i * 7 + j] = bf16_rne(m);
        }
    }
    __syncthreads();
    // coalesced copy-out: X[r][by*256*49 + t]
    unsigned int* dst = (unsigned int*)(X + r * 25088 + blockIdx.y * (256 * 49));
    const unsigned int* src = (const unsigned int*)tile;
    for (int t = threadIdx.x; t < 256 * 49 / 2; t += 256) dst[t] = src[t];
}

// ---------------- staged GEMM: P[sp] = A[128 x Kchunk] * B[K][4096] ---------
// 512 threads (8 waves). Block tile 128x128, BK=32. 3-buffer LDS ring,
// stage distance 2, counted vmcnt(3): tile t+1 and t+2 stay in flight across
// the single raw s_barrier per K-step (prefetch is never drained).
// Safety: reads of tile t complete before barrier(t) (MFMA operand deps);
// stage(t+2) issues after barrier(t-1), i.e. after all waves read tile t-1
// from the same buffer. Requires nsteps >= 2.
template <int LDA>
__global__ __launch_bounds__(512, 4)
void gemm_big_kernel(const unsigned short* __restrict__ A,  // bf16 [128][LDA]
                     const float* __restrict__ B,           // [K][4096]
                     float* __restrict__ P,                 // [S][128][4096]
                     int Kchunk)
{
    constexpr int N = 4096;
    __shared__ float          Bt[3][32 * 128];   // 3 x 16 KB
    __shared__ unsigned short At[3][128 * 32];   // 3 x  8 KB

    const int tid  = threadIdx.x;
    const int lane = tid & 63;
    const int w    = tid >> 6;        // wave 0..7
    const int q    = lane >> 4;       // k-quad 0..3
    const int r    = lane & 15;       // row-within-tile / col-within-16
    const int colb = blockIdx.x * 128;
    const int sp   = blockIdx.y;
    const int kbeg = sp * Kchunk;
    const int nsteps = Kchunk >> 5;

    const int b_rd = q * (8 * 128) + w * 16 + r;     // floats into Bt tile
    const int a_rd = r * 64 + q * 16;                // bytes  into At tile

    f32x4 acc[8] = {};

    // stage one BK=32 tile: 3 gl16 per wave (2 for B, 1 for A)
    auto stage = [&](int buf, int t) {
        const int k0 = kbeg + t * 32;
        int i0 = w * 64 + lane;
        const float* g0 = B + (size_t)(k0 + (i0 >> 5)) * N + colb + ((i0 & 31) << 2);
        gl16(g0, (char*)&Bt[buf][0] + w * 1024);
        int i1 = i0 + 512;
        const float* g1 = B + (size_t)(k0 + (i1 >> 5)) * N + colb + ((i1 & 31) << 2);
        gl16(g1, (char*)&Bt[buf][0] + 8192 + w * 1024);
        const unsigned short* g = A + (size_t)(i0 >> 2) * LDA + k0 + ((i0 & 3) << 3);
        gl16(g, (char*)&At[buf][0] + w * 1024);
    };

    // prologue: tiles 0 and 1 in flight; wait only for tile 0 (vmcnt<=3)
    stage(0, 0);
    stage(1, 1);
    asm volatile("s_waitcnt vmcnt(3)" ::: "memory");
    __builtin_amdgcn_s_barrier();

    int cur = 0;                       // buffer holding tile t
    for (int t = 0; t < nsteps; ++t) {
        const int nx2 = (cur == 0) ? 2 : cur - 1;   // (t+2) % 3

        // ds-reads of tile t (issue before staging so they start early)
        const float* btp = &Bt[cur][b_rd];
        float bv[8];
#pragma unroll
        for (int j = 0; j < 8; ++j) bv[j] = btp[j * 128];
        short8 afrag[8];
        const char* atp = (const char*)&At[cur][0] + a_rd;
#pragma unroll
        for (int t8 = 0; t8 < 8; ++t8)
            afrag[t8] = *(const short8*)(atp + t8 * 1024);

        if (t + 2 < nsteps) stage(nx2, t + 2);

        short8 bfrag;
#pragma unroll
        for (int j = 0; j < 8; ++j) bfrag[j] = (short)bf16_rne(bv[j]);
#pragma unroll
        for (int t8 = 0; t8 < 8; ++t8)
            acc[t8] = __builtin_amdgcn_mfma_f32_16x16x32_bf16(afrag[t8], bfrag, acc[t8], 0, 0, 0);

        // tile t+1 must have landed before the barrier; keep t+2 in flight
        if (t + 2 < nsteps) {
            asm volatile("s_waitcnt vmcnt(3)" ::: "memory");
        } else {
            asm volatile("s_waitcnt vmcnt(0)" ::: "memory");
        }
        __builtin_amdgcn_s_barrier();
        cur = (cur == 2) ? 0 : cur + 1;             // (t+1) % 3
    }

    float* p = P + (size_t)sp * 128 * N + colb + w * 16 + r;
#pragma unroll
    for (int t8 = 0; t8 < 8; ++t8)
#pragma unroll
        for (int rr = 0; rr < 4; ++rr)
            p[(size_t)(16 * t8 + q * 4 + rr) * N] = acc[t8][rr];
}

// ---------------- head GEMM: cols 0..83 -> W_loc, 84..104 -> W_score --------
__global__ __launch_bounds__(256, 4)
void gemm_head_kernel(const unsigned short* __restrict__ A,  // h2 bf16 [128][4096]
                      const float* __restrict__ Wl,          // [4096][84]
                      const float* __restrict__ Ws,          // [4096][21]
                      float* __restrict__ P,                 // [S][128][112]
                      int Kchunk)
{
    constexpr int LDA = 4096;
    const int lane = threadIdx.x & 63;
    const int w    = threadIdx.x >> 6;
    const int q    = lane >> 4;
    const int col  = blockIdx.x * 64 + w * 16 + (lane & 15);  // 0..127
    const int sp   = blockIdx.y;
    const int kbeg = sp * Kchunk;

    int stride; const float* bp;
    if (col < 84)       { stride = 84; bp = Wl + col; }
    else if (col < 105) { stride = 21; bp = Ws + (col - 84); }
    else                { stride = 0;  bp = Ws; }
    bp += (size_t)(kbeg + q * 8) * stride;

    f32x4 acc[8] = {};
    const unsigned short* a_base = A + (lane & 15) * LDA + kbeg + q * 8;

    for (int ks = 0; ks < Kchunk; ks += 32) {
        short8 afrag[8];
#pragma unroll
        for (int t = 0; t < 8; ++t)
            afrag[t] = *(const short8*)(a_base + (size_t)t * 16 * LDA);
        short8 bfrag;
#pragma unroll
        for (int j = 0; j < 8; ++j)
            bfrag[j] = (short)bf16_rne(bp[(size_t)j * stride]);
#pragma unroll
        for (int t = 0; t < 8; ++t)
            acc[t] = __builtin_amdgcn_mfma_f32_16x16x32_bf16(afrag[t], bfrag, acc[t], 0, 0, 0);
        a_base += 32;
        bp += (size_t)32 * stride;
    }

    if (col < 112) {
        float* p = P + (size_t)sp * 128 * 112 + col;
#pragma unroll
        for (int t = 0; t < 8; ++t)
#pragma unroll
            for (int r = 0; r < 4; ++r)
                p[(size_t)(16 * t + q * 4 + r) * 112] = acc[t][r];
    }
}

// ---------------- split-K reduce + bias + relu -> bf16 ----------------------
__global__ void reduce_relu_kernel(const float* __restrict__ P,     // [16][128][4096]
                                   const float* __restrict__ bias,  // [4096]
                                   unsigned short* __restrict__ H)  // bf16 [128][4096]
{
    const int e = blockIdx.x * 256 + threadIdx.x;
    if (e >= 128 * 4096) return;
    constexpr int NT = 128 * 4096;
    float s = 0.f;
#pragma unroll
    for (int i = 0; i < 16; ++i) s += P[(size_t)i * NT + e];
    s += bias[e & 4095];
    s = fmaxf(s, 0.f);
    H[e] = bf16_rne(s);
}

// ---------------- head reduce + bias -> d_out (locs then scores) ------------
__global__ void reduce_head_kernel(const float* __restrict__ P,   // [64][128][112]
                                   const float* __restrict__ bl,  // [84]
                                   const float* __restrict__ bs,  // [21]
                                   float* __restrict__ out)       // 128*84 + 128*21
{
    const int e = blockIdx.x * 256 + threadIdx.x;
    if (e >= 128 * 112) return;
    const int m = e / 112, col = e % 112;
    if (col >= 105) return;
    float s = 0.f;
#pragma unroll
    for (int i = 0; i < 64; ++i) s += P[(size_t)i * 128 * 112 + e];
    if (col < 84) out[m * 84 + col] = s + bl[col];
    else          out[128 * 84 + m * 21 + (col - 84)] = s + bs[col - 84];
}

extern "C" void kernel_launch(void* const* d_in, const int* in_sizes, int n_in,
                              void* d_out, int out_size, void* d_ws, size_t ws_size,
                              hipStream_t stream)
{
    const float* feats = (const float*)d_in[0];
    const float* rois  = (const float*)d_in[1];
    const float* W1    = (const float*)d_in[2];
    const float* b1    = (const float*)d_in[3];
    const float* W2    = (const float*)d_in[4];
    const float* b2    = (const float*)d_in[5];
    const float* Wl    = (const float*)d_in[6];
    const float* bl    = (const float*)d_in[7];
    const float* Wsc   = (const float*)d_in[8];
    const float* bsc   = (const float*)d_in[9];
    float* out = (float*)d_out;

    char* ws = (char*)d_ws;
    unsigned short* X  = (unsigned short*)(ws);              // 6,422,528 B
    unsigned short* H1 = (unsigned short*)(ws + 6422528);    // 1,048,576 B
    unsigned short* H2 = (unsigned short*)(ws + 7471104);    // 1,048,576 B
    float* FT          = (float*)(ws + 8519680);             // 3,891,200 B
    float* P           = (float*)(ws + 12410880);            // 33.5 MB partials

    transpose_kernel<<<dim3(60, 16), dim3(32, 8), 0, stream>>>(feats, FT);
    pool_kernel<<<dim3(128, 2), 256, 0, stream>>>(FT, rois, X);

    // GEMM1: K=25088, split 16 -> Kchunk 1568 (49 steps), 32x16=512 blocks
    gemm_big_kernel<25088><<<dim3(32, 16), 512, 0, stream>>>(X, W1, P, 1568);
    reduce_relu_kernel<<<2048, 256, 0, stream>>>(P, b1, H1);

    // GEMM2: K=4096, split 16 -> Kchunk 256 (8 steps)
    gemm_big_kernel<4096><<<dim3(32, 16), 512, 0, stream>>>(H1, W2, P, 256);
    reduce_relu_kernel<<<2048, 256, 0, stream>>>(P, b2, H2);

    // head: K=4096, split 64 -> Kchunk 64; 2 n-blocks cover 105 (pad 112/128)
    gemm_head_kernel<<<dim3(2, 64), 256, 0, stream>>>(H2, Wl, Wsc, P, 64);
    reduce_head_kernel<<<56, 256, 0, stream>>>(P, bl, bsc, out);
}

// Round 3
// 692.670 us; speedup vs baseline: 1.0693x; 1.0693x over previous
//
#include <hip/hip_runtime.h>

// ROI head: pool -> x@W1 relu -> @W2 relu -> @[W_loc|W_score]
// HBM-bound on fp32 weight streaming (~480MB, read once per launch).
// Big GEMMs: LDS-staged via global_load_lds dwordx4, 3-buffer ring,
// stage-distance 2, counted s_waitcnt vmcnt(3) (prefetch never drained),
// XCD-aware block remap so blocks sharing an A-chunk land on one XCD's L2.
// Pool: unrolled 7x7 bins (register-resident bounds), runtime <=4-wide
// windows (typical 2x2) -- scratch-free without load blowup.

typedef short short8 __attribute__((ext_vector_type(8)));
typedef float f32x4 __attribute__((ext_vector_type(4)));

__device__ __forceinline__ unsigned short bf16_rne(float f) {
    unsigned int u = __builtin_bit_cast(unsigned int, f);
    unsigned int r = (u + 0x7FFFu + ((u >> 16) & 1u)) >> 16;
    return (unsigned short)r;
}

// async global->LDS, 16B per lane; lptr must be wave-uniform (HW scatters
// lane i to lptr + 16*i). gptr is per-lane.
__device__ __forceinline__ void gl16(const void* g, void* l) {
    __builtin_amdgcn_global_load_lds(
        (const __attribute__((address_space(1))) unsigned int*)g,
        (__attribute__((address_space(3))) unsigned int*)l, 16, 0, 0);
}

// ---------------- transpose F[512][1900] -> FT[1900][512] -------------------
__global__ void transpose_kernel(const float* __restrict__ F,
                                 float* __restrict__ FT)
{
    __shared__ float t[32][33];
    const int xs = blockIdx.x * 32;   // spatial 0..1899
    const int cs = blockIdx.y * 32;   // channel 0..511
    const int tx = threadIdx.x, ty = threadIdx.y;  // 32 x 8
#pragma unroll
    for (int k = 0; k < 4; ++k) {
        int cc = cs + ty + k * 8;
        int xx = xs + tx;
        if (xx < 1900) t[ty + k * 8][tx] = F[cc * 1900 + xx];
    }
    __syncthreads();
#pragma unroll
    for (int k = 0; k < 4; ++k) {
        int xx = xs + ty + k * 8;
        int cc = cs + tx;
        if (xx < 1900) FT[xx * 512 + cc] = t[tx][ty + k * 8];
    }
}

// ---------------- pooling: FT[1900][512] -> X bf16 [128][25088] -------------
// ROI sides <= 256px => L <= 17 feature px => adaptive window <= 4 per axis
// (validated by round-2 pass with cap 4). Outer 7x7 unrolled so bin bounds
// are compile-time-indexed (registers, no scratch); windows runtime-bound
// (typical 2x2) so we don't issue 16 loads per bin.
__global__ void pool_kernel(const float* __restrict__ FT,
                            const float* __restrict__ rois,
                            unsigned short* __restrict__ X)
{
    __shared__ unsigned short tile[256 * 49];
    const int r = blockIdx.x;
    const int c = blockIdx.y * 256 + threadIdx.x;   // channel
    const float4 rv = ((const float4*)rois)[r];
    const int y0 = (int)truncf(rv.x * 0.0625f);
    const int x0 = (int)truncf(rv.y * 0.0625f);
    const int y2 = (int)ceilf (rv.z * 0.0625f);
    const int x3 = (int)ceilf (rv.w * 0.0625f);
    const int Ly = y2 - y0, Lx = x3 - x0;

    int rb[7], re[7], cb[7], ce[7];
#pragma unroll
    for (int i = 0; i < 7; ++i) {
        rb[i] = y0 + (i * Ly) / 7;
        re[i] = min(min(y0 + ((i + 1) * Ly + 6) / 7, rb[i] + 4), 38);
        cb[i] = x0 + (i * Lx) / 7;
        ce[i] = min(min(x0 + ((i + 1) * Lx + 6) / 7, cb[i] + 4), 50);
    }

    const float* base = FT + (size_t)c;
#pragma unroll
    for (int i = 0; i < 7; ++i) {
#pragma unroll
        for (int j = 0; j < 7; ++j) {
            float m = -3.4e38f;
            for (int rr = rb[i]; rr < re[i]; ++rr)
                for (int cc = cb[j]; cc < ce[j]; ++cc)
                    m = fmaxf(m, base[(size_t)(rr * 50 + cc) * 512]);
            tile[threadIdx.x * 49 + i * 7 + j] = bf16_rne(m);
        }
    }
    __syncthreads();
    // coalesced copy-out: X[r][by*256*49 + t]
    unsigned int* dst = (unsigned int*)(X + r * 25088 + blockIdx.y * (256 * 49));
    const unsigned int* src = (const unsigned int*)tile;
    for (int t = threadIdx.x; t < 256 * 49 / 2; t += 256) dst[t] = src[t];
}

// ---------------- staged GEMM: P[sp] = A[128 x Kchunk] * B[K][4096] ---------
// 512 threads (8 waves). Block tile 128x128, BK=32. 3-buffer LDS ring,
// stage distance 2, counted vmcnt(3): tiles t+1, t+2 stay in flight across
// the single raw s_barrier per K-step (prefetch never drained).
// Safety: reads of tile t complete before barrier(t) (MFMA operand deps);
// stage(t+2) issues after barrier(t-1), i.e. after all waves read tile t-1
// from the buffer being overwritten. Requires nsteps >= 2.
// XCD remap: linear bid round-robins XCDs, so give each XCD a contiguous
// run of same-sp blocks -> the shared A-chunk (392KB) stays in that L2.
// Assumes gridDim.x == 32 and gridDim.y % 8 == 0.
template <int LDA>
__global__ __launch_bounds__(512, 4)
void gemm_big_kernel(const unsigned short* __restrict__ A,  // bf16 [128][LDA]
                     const float* __restrict__ B,           // [K][4096]
                     float* __restrict__ P,                 // [S][128][4096]
                     int Kchunk)
{
    constexpr int N = 4096;
    __shared__ float          Bt[3][32 * 128];   // 3 x 16 KB
    __shared__ unsigned short At[3][128 * 32];   // 3 x  8 KB

    const int tid  = threadIdx.x;
    const int lane = tid & 63;
    const int w    = tid >> 6;        // wave 0..7
    const int q    = lane >> 4;       // k-quad 0..3
    const int r    = lane & 15;       // row-within-tile / col-within-16
    // XCD-aware (bx, sp) remap (bijective for gridDim.y % 8 == 0)
    const int bid  = blockIdx.x + (blockIdx.y << 5);
    const int xcd  = bid & 7;
    const int li   = bid >> 3;
    const int spn  = gridDim.y >> 3;           // sp values per XCD
    const int sp   = xcd * spn + (li >> 5);    // li / 32
    const int bx   = li & 31;
    const int colb = bx * 128;
    const int kbeg = sp * Kchunk;
    const int nsteps = Kchunk >> 5;

    const int b_rd = q * (8 * 128) + w * 16 + r;     // floats into Bt tile
    const int a_rd = r * 64 + q * 16;                // bytes  into At tile

    f32x4 acc[8] = {};

    // stage one BK=32 tile: 3 gl16 per wave (2 for B, 1 for A)
    auto stage = [&](int buf, int t) {
        const int k0 = kbeg + t * 32;
        int i0 = w * 64 + lane;
        const float* g0 = B + (size_t)(k0 + (i0 >> 5)) * N + colb + ((i0 & 31) << 2);
        gl16(g0, (char*)&Bt[buf][0] + w * 1024);
        int i1 = i0 + 512;
        const float* g1 = B + (size_t)(k0 + (i1 >> 5)) * N + colb + ((i1 & 31) << 2);
        gl16(g1, (char*)&Bt[buf][0] + 8192 + w * 1024);
        const unsigned short* g = A + (size_t)(i0 >> 2) * LDA + k0 + ((i0 & 3) << 3);
        gl16(g, (char*)&At[buf][0] + w * 1024);
    };

    // prologue: tiles 0 and 1 in flight; wait only for tile 0 (vmcnt<=3)
    stage(0, 0);
    stage(1, 1);
    asm volatile("s_waitcnt vmcnt(3)" ::: "memory");
    __builtin_amdgcn_s_barrier();

    int cur = 0;                       // buffer holding tile t
    for (int t = 0; t < nsteps; ++t) {
        const int nx2 = (cur == 0) ? 2 : cur - 1;   // (t+2) % 3

        // ds-reads of tile t (issue before staging so they start early)
        const float* btp = &Bt[cur][b_rd];
        float bv[8];
#pragma unroll
        for (int j = 0; j < 8; ++j) bv[j] = btp[j * 128];
        short8 afrag[8];
        const char* atp = (const char*)&At[cur][0] + a_rd;
#pragma unroll
        for (int t8 = 0; t8 < 8; ++t8)
            afrag[t8] = *(const short8*)(atp + t8 * 1024);

        if (t + 2 < nsteps) stage(nx2, t + 2);

        short8 bfrag;
#pragma unroll
        for (int j = 0; j < 8; ++j) bfrag[j] = (short)bf16_rne(bv[j]);
#pragma unroll
        for (int t8 = 0; t8 < 8; ++t8)
            acc[t8] = __builtin_amdgcn_mfma_f32_16x16x32_bf16(afrag[t8], bfrag, acc[t8], 0, 0, 0);

        // tile t+1 must have landed before the barrier; keep t+2 in flight
        if (t + 2 < nsteps) {
            asm volatile("s_waitcnt vmcnt(3)" ::: "memory");
        } else {
            asm volatile("s_waitcnt vmcnt(0)" ::: "memory");
        }
        __builtin_amdgcn_s_barrier();
        cur = (cur == 2) ? 0 : cur + 1;             // (t+1) % 3
    }

    float* p = P + (size_t)sp * 128 * N + colb + w * 16 + r;
#pragma unroll
    for (int t8 = 0; t8 < 8; ++t8)
#pragma unroll
        for (int rr = 0; rr < 4; ++rr)
            p[(size_t)(16 * t8 + q * 4 + rr) * N] = acc[t8][rr];
}

// ---------------- head GEMM: cols 0..83 -> W_loc, 84..104 -> W_score --------
__global__ __launch_bounds__(256, 4)
void gemm_head_kernel(const unsigned short* __restrict__ A,  // h2 bf16 [128][4096]
                      const float* __restrict__ Wl,          // [4096][84]
                      const float* __restrict__ Ws,          // [4096][21]
                      float* __restrict__ P,                 // [S][128][112]
                      int Kchunk)
{
    constexpr int LDA = 4096;
    const int lane = threadIdx.x & 63;
    const int w    = threadIdx.x >> 6;
    const int q    = lane >> 4;
    const int col  = blockIdx.x * 64 + w * 16 + (lane & 15);  // 0..127
    const int sp   = blockIdx.y;
    const int kbeg = sp * Kchunk;

    int stride; const float* bp;
    if (col < 84)       { stride = 84; bp = Wl + col; }
    else if (col < 105) { stride = 21; bp = Ws + (col - 84); }
    else                { stride = 0;  bp = Ws; }
    bp += (size_t)(kbeg + q * 8) * stride;

    f32x4 acc[8] = {};
    const unsigned short* a_base = A + (lane & 15) * LDA + kbeg + q * 8;

    for (int ks = 0; ks < Kchunk; ks += 32) {
        short8 afrag[8];
#pragma unroll
        for (int t = 0; t < 8; ++t)
            afrag[t] = *(const short8*)(a_base + (size_t)t * 16 * LDA);
        short8 bfrag;
#pragma unroll
        for (int j = 0; j < 8; ++j)
            bfrag[j] = (short)bf16_rne(bp[(size_t)j * stride]);
#pragma unroll
        for (int t = 0; t < 8; ++t)
            acc[t] = __builtin_amdgcn_mfma_f32_16x16x32_bf16(afrag[t], bfrag, acc[t], 0, 0, 0);
        a_base += 32;
        bp += (size_t)32 * stride;
    }

    if (col < 112) {
        float* p = P + (size_t)sp * 128 * 112 + col;
#pragma unroll
        for (int t = 0; t < 8; ++t)
#pragma unroll
            for (int r = 0; r < 4; ++r)
                p[(size_t)(16 * t + q * 4 + r) * 112] = acc[t][r];
    }
}

// ---------------- split-K reduce + bias + relu -> bf16 (float4) -------------
template <int S>
__global__ void reduce_relu_kernel(const float* __restrict__ P,     // [S][128][4096]
                                   const float* __restrict__ bias,  // [4096]
                                   unsigned short* __restrict__ H)  // bf16 [128][4096]
{
    constexpr int NT4 = 128 * 4096 / 4;
    const int e4 = blockIdx.x * 256 + threadIdx.x;
    if (e4 >= NT4) return;
    const float4* P4 = (const float4*)P;
    float4 s = P4[e4];
#pragma unroll
    for (int i = 1; i < S; ++i) {
        float4 v = P4[(size_t)i * NT4 + e4];
        s.x += v.x; s.y += v.y; s.z += v.z; s.w += v.w;
    }
    const float4 b = *(const float4*)(bias + ((e4 & 1023) << 2));
    unsigned int lo = (unsigned int)bf16_rne(fmaxf(s.x + b.x, 0.f))
                    | ((unsigned int)bf16_rne(fmaxf(s.y + b.y, 0.f)) << 16);
    unsigned int hi = (unsigned int)bf16_rne(fmaxf(s.z + b.z, 0.f))
                    | ((unsigned int)bf16_rne(fmaxf(s.w + b.w, 0.f)) << 16);
    uint2 o; o.x = lo; o.y = hi;
    *(uint2*)(H + (size_t)e4 * 4) = o;
}

// ---------------- head reduce + bias -> d_out (locs then scores) ------------
__global__ void reduce_head_kernel(const float* __restrict__ P,   // [64][128][112]
                                   const float* __restrict__ bl,  // [84]
                                   const float* __restrict__ bs,  // [21]
                                   float* __restrict__ out)       // 128*84 + 128*21
{
    const int e = blockIdx.x * 256 + threadIdx.x;
    if (e >= 128 * 112) return;
    const int m = e / 112, col = e % 112;
    if (col >= 105) return;
    float s = 0.f;
#pragma unroll
    for (int i = 0; i < 64; ++i) s += P[(size_t)i * 128 * 112 + e];
    if (col < 84) out[m * 84 + col] = s + bl[col];
    else          out[128 * 84 + m * 21 + (col - 84)] = s + bs[col - 84];
}

extern "C" void kernel_launch(void* const* d_in, const int* in_sizes, int n_in,
                              void* d_out, int out_size, void* d_ws, size_t ws_size,
                              hipStream_t stream)
{
    const float* feats = (const float*)d_in[0];
    const float* rois  = (const float*)d_in[1];
    const float* W1    = (const float*)d_in[2];
    const float* b1    = (const float*)d_in[3];
    const float* W2    = (const float*)d_in[4];
    const float* b2    = (const float*)d_in[5];
    const float* Wl    = (const float*)d_in[6];
    const float* bl    = (const float*)d_in[7];
    const float* Wsc   = (const float*)d_in[8];
    const float* bsc   = (const float*)d_in[9];
    float* out = (float*)d_out;

    char* ws = (char*)d_ws;
    unsigned short* X  = (unsigned short*)(ws);              // 6,422,528 B
    unsigned short* H1 = (unsigned short*)(ws + 6422528);    // 1,048,576 B
    unsigned short* H2 = (unsigned short*)(ws + 7471104);    // 1,048,576 B
    float* FT          = (float*)(ws + 8519680);             // 3,891,200 B
    float* P           = (float*)(ws + 12410880);            // 33.5 MB partials

    transpose_kernel<<<dim3(60, 16), dim3(32, 8), 0, stream>>>(feats, FT);
    pool_kernel<<<dim3(128, 2), 256, 0, stream>>>(FT, rois, X);

    // GEMM1: K=25088, split 16 -> Kchunk 1568 (49 steps), 32x16=512 blocks
    gemm_big_kernel<25088><<<dim3(32, 16), 512, 0, stream>>>(X, W1, P, 1568);
    reduce_relu_kernel<16><<<512, 256, 0, stream>>>(P, b1, H1);

    // GEMM2: K=4096, split 8 -> Kchunk 512 (16 steps), 32x8=256 blocks
    // (halves P partial traffic vs split 16)
    gemm_big_kernel<4096><<<dim3(32, 8), 512, 0, stream>>>(H1, W2, P, 512);
    reduce_relu_kernel<8><<<512, 256, 0, stream>>>(P, b2, H2);

    // head: K=4096, split 64 -> Kchunk 64; 2 n-blocks cover 105 (pad 112/128)
    gemm_head_kernel<<<dim3(2, 64), 256, 0, stream>>>(H2, Wl, Wsc, P, 64);
    reduce_head_kernel<<<56, 256, 0, stream>>>(P, bl, bsc, out);
}